// Round 8
// baseline (373.589 us; speedup 1.0000x reference)
//
#include <hip/hip_runtime.h>
#include <hip/hip_cooperative_groups.h>
#include <hip/hip_bf16.h>

namespace cg = cooperative_groups;

// n=M=10000 nodes, a=K=512, b=N=256, E=320000 edges.  M must be <= MCAP.

#define NB   64    // edge-partition blocks for hist/fill
#define GMAX 512
#define MCAP 10240
#define DYN_LDS 40960

typedef __attribute__((ext_vector_type(8))) short bf16x8;
typedef __attribute__((ext_vector_type(4))) float f32x4;

__device__ inline ushort f2bf(float f) {
    uint b = __float_as_uint(f);
    return (ushort)((b + 0x7FFFu + ((b >> 16) & 1u)) >> 16);  // RNE
}
__device__ inline float bf2f(ushort u) { return __uint_as_float((uint)u << 16); }

// ---------------------------------------------------------------------------
// MFMA GEMM tile (128x128, 4 waves x 4x4 frags of 16x16x32 bf16).
__device__ void mm_tile(int tile, char* smem,
                        const ushort* __restrict__ Hb,
                        const ushort* __restrict__ Wt,
                        ushort* __restrict__ HWb, int M, int N, int K) {
    ushort (*As)[40] = (ushort (*)[40])smem;
    ushort (*Bs)[40] = (ushort (*)[40])(smem + 128 * 40 * 2);
    int mblk = (M + 127) >> 7;
    int m0 = (tile % mblk) * 128, n0 = (tile / mblk) * 128;
    int tid = threadIdx.x;
    int wid = tid >> 6, lane = tid & 63;
    int wm = (wid >> 1) * 64, wn = (wid & 1) * 64;
    int frow = lane & 15, fg = (lane >> 4) * 8;
    f32x4 acc[4][4] = {};
    for (int k0 = 0; k0 < K; k0 += 32) {
        #pragma unroll
        for (int h = 0; h < 2; ++h) {
            int chunk = tid + 256 * h;
            int row = chunk >> 2, kc = (chunk & 3) * 8;
            int gr = m0 + row;
            int4 va = make_int4(0, 0, 0, 0);
            if (gr < M) va = *(const int4*)&Hb[(size_t)gr * K + k0 + kc];
            *(int4*)&As[row][kc] = va;
            int4 vb = *(const int4*)&Wt[(size_t)(n0 + row) * K + k0 + kc];
            *(int4*)&Bs[row][kc] = vb;
        }
        __syncthreads();
        bf16x8 av[4], bv[4];
        #pragma unroll
        for (int i = 0; i < 4; ++i)
            av[i] = *(const bf16x8*)&As[wm + i * 16 + frow][fg];
        #pragma unroll
        for (int j = 0; j < 4; ++j)
            bv[j] = *(const bf16x8*)&Bs[wn + j * 16 + frow][fg];
        #pragma unroll
        for (int i = 0; i < 4; ++i)
            #pragma unroll
            for (int j = 0; j < 4; ++j)
                acc[i][j] = __builtin_amdgcn_mfma_f32_16x16x32_bf16(av[i], bv[j], acc[i][j], 0, 0, 0);
        __syncthreads();
    }
    // C/D map: col=lane&15, row=(lane>>4)*4+rr  [verified m89/m91]
    int orow = (lane >> 4) * 4, ocol = lane & 15;
    #pragma unroll
    for (int i = 0; i < 4; ++i) {
        #pragma unroll
        for (int rr = 0; rr < 4; ++rr) {
            int grow = m0 + wm + i * 16 + orow + rr;
            if (grow < M) {
                #pragma unroll
                for (int j = 0; j < 4; ++j) {
                    int gcol = n0 + wn + j * 16 + ocol;
                    HWb[(size_t)grow * N + gcol] = f2bf(acc[i][j][rr]);
                }
            }
        }
    }
}

// ===========================================================================
// Cooperative fused pipeline (fast path).  G decided at runtime (>=64).
__global__ __launch_bounds__(256) void k_mega(const int* __restrict__ st,
                                              const float* __restrict__ H,
                                              const float* __restrict__ W,
                                              const float* __restrict__ emb_w,
                                              const float* __restrict__ emb_b,
                                              const float* __restrict__ rv,
                                              float* __restrict__ q,
                                              float* __restrict__ p,
                                              ushort* __restrict__ Hb,
                                              ushort* __restrict__ Wt,
                                              ushort* __restrict__ HWb,
                                              uint* __restrict__ parthist,
                                              int* __restrict__ crosscnt,
                                              float* __restrict__ selfmul,
                                              int* __restrict__ offsets,
                                              int* __restrict__ colidx,
                                              uint* __restrict__ tileCtr,
                                              int E, int M, int N, int K, int tiles) {
    cg::grid_group grid = cg::this_grid();
    extern __shared__ char smem[];
    __shared__ int tshare;
    const int G = gridDim.x;
    int bid = blockIdx.x, tid = threadIdx.x;
    int wid = tid >> 6, lane = tid & 63;

    // ---- P0: q = W @ emb_w (f32-exact) ; Wt = bf16(W^T) ; zero tileCtr ----
    if (bid == 0 && tid == 0) *tileCtr = 0;
    {
        int nq = K / 4;                    // 128 units, 4 rows each
        int nt = (K / 32) * (N / 32);      // 128 transpose units
        for (int u = bid; u < nq + nt; u += G) {
            if (u < nq) {
                int k = u * 4 + wid;
                float4 w4 = *(const float4*)&W[(size_t)k * N + lane * 4];
                float4 e4 = *(const float4*)&emb_w[lane * 4];
                float s = w4.x * e4.x + w4.y * e4.y + w4.z * e4.z + w4.w * e4.w;
                #pragma unroll
                for (int d = 32; d; d >>= 1) s += __shfl_down(s, d);
                if (lane == 0) q[k] = s;
            } else {
                float (*ts)[33] = (float (*)[33])smem;
                int idx = u - nq;
                int k0 = (idx % (K / 32)) * 32;
                int n0 = (idx / (K / 32)) * 32;
                int x = tid & 31, y = tid >> 5;  // 32x8
                __syncthreads();
                #pragma unroll
                for (int i = 0; i < 4; ++i) {
                    int kk = y + i * 8;
                    ts[kk][x] = W[(size_t)(k0 + kk) * N + n0 + x];
                }
                __syncthreads();
                #pragma unroll
                for (int i = 0; i < 4; ++i) {
                    int nn = y + i * 8;
                    Wt[(size_t)(n0 + nn) * K + k0 + x] = f2bf(ts[x][nn]);
                }
            }
        }
    }
    __threadfence();
    grid.sync();

    // ---- P1: Hb = bf16(H), p = (H@q + emb_b)*rv (f32-exact routing) ----
    {
        int units = (M + 3) / 4;
        for (int u = bid; u < units; u += G) {
            int i = u * 4 + wid;
            if (i < M) {
                const float* h = H + (size_t)i * K;
                float s = 0.f;
                for (int o = lane * 8; o < K; o += 512) {
                    float4 a = *(const float4*)&h[o];
                    float4 b = *(const float4*)&h[o + 4];
                    float4 qa = *(const float4*)&q[o];
                    float4 qb = *(const float4*)&q[o + 4];
                    s += a.x * qa.x + a.y * qa.y + a.z * qa.z + a.w * qa.w
                       + b.x * qb.x + b.y * qb.y + b.z * qb.z + b.w * qb.w;
                    ushort uu[8] = {f2bf(a.x), f2bf(a.y), f2bf(a.z), f2bf(a.w),
                                    f2bf(b.x), f2bf(b.y), f2bf(b.z), f2bf(b.w)};
                    *(int4*)&Hb[(size_t)i * K + o] = *(int4*)uu;
                }
                #pragma unroll
                for (int d = 32; d; d >>= 1) s += __shfl_down(s, d);
                if (lane == 0) p[i] = (s + emb_b[0]) * rv[0];
            }
        }
    }
    __threadfence();
    grid.sync();

    // ---- P2: hist (blocks [0,NB)), then ALL blocks drain mm-tile pool ----
    if (bid < NB) {
        uint* h = (uint*)smem;
        for (int i = tid; i < M; i += 256) h[i] = 0;
        __syncthreads();
        int epb = (E + NB - 1) / NB;
        int beg = bid * epb, end = min(beg + epb, E);
        for (int e = beg + tid; e < end; e += 256) {
            int u = st[e], v = st[E + e];
            uint inc = (p[u] > p[v]) ? 1u : (1u << 16);
            atomicAdd(&h[u], inc);
            atomicAdd(&h[v], inc);
        }
        __syncthreads();
        for (int i = tid; i < M; i += 256)
            parthist[(size_t)bid * M + i] = h[i];
    }
    for (;;) {
        __syncthreads();
        if (tid == 0) tshare = (int)atomicAdd(tileCtr, 1u);
        __syncthreads();
        int t = tshare;
        if (t >= tiles) break;
        mm_tile(t, smem, Hb, Wt, HWb, M, N, K);
    }
    __threadfence();
    grid.sync();

    // ---- P3: per-row merge over NB partials (batched 32-wide loads) ----
    {
        int r = bid * 256 + tid;
        if (bid < (M + 255) / 256 && r < M) {
            uint crun = 0, srun = 0;
            for (int c = 0; c < NB / 32; ++c) {
                uint vals[32];
                #pragma unroll
                for (int i = 0; i < 32; ++i)
                    vals[i] = parthist[(size_t)(c * 32 + i) * M + r];
                #pragma unroll
                for (int i = 0; i < 32; ++i) {
                    parthist[(size_t)(c * 32 + i) * M + r] = crun;
                    crun += vals[i] & 0xFFFFu;
                    srun += vals[i] >> 16;
                }
            }
            crosscnt[r] = (int)crun;
            selfmul[r] = 1.0f + (float)srun;
        }
    }
    __threadfence();
    grid.sync();

    // ---- P3b: exclusive scan -> offsets (block 0) ----
    if (bid == 0) {
        __shared__ int s[256];
        int t = tid;
        int chunk = (M + 255) / 256;
        int cb = t * chunk;
        int ce = min(cb + chunk, M);
        int sum = 0;
        for (int i = cb; i < ce; ++i) sum += crosscnt[i];
        s[t] = sum;
        __syncthreads();
        for (int d = 1; d < 256; d <<= 1) {
            int val = (t >= d) ? s[t - d] : 0;
            __syncthreads();
            s[t] += val;
            __syncthreads();
        }
        int run = (t == 0) ? 0 : s[t - 1];
        for (int i = cb; i < ce; ++i) {
            offsets[i] = run;
            run += crosscnt[i];
        }
        if (t == 255) offsets[M] = run;
    }
    __threadfence();
    grid.sync();

    // ---- P4: slot assignment (LDS cursors; cross edges only) ----
    if (bid < NB) {
        int* cur = (int*)smem;
        for (int i = tid; i < M; i += 256)
            cur[i] = offsets[i] + (int)parthist[(size_t)bid * M + i];
        __syncthreads();
        int epb = (E + NB - 1) / NB;
        int beg = bid * epb, end = min(beg + epb, E);
        for (int e = beg + tid; e < end; e += 256) {
            int u = st[e], v = st[E + e];
            if (p[u] > p[v]) {
                int su = atomicAdd(&cur[u], 1);
                colidx[su] = v;
                int sv = atomicAdd(&cur[v], 1);
                colidx[sv] = u;
            }
        }
    }
}

// ===========================================================================
// Fallback pipeline (verified R6 structure).
__global__ __launch_bounds__(256) void k_prep(const float* __restrict__ W,
                                              const float* __restrict__ emb_w,
                                              float* __restrict__ q,
                                              ushort* __restrict__ Wt,
                                              uint* __restrict__ done,
                                              int K, int N) {
    int b = blockIdx.x;
    int nq = K / 4;
    if (b < nq) {
        int wave = threadIdx.x >> 6;
        int lane = threadIdx.x & 63;
        int k = b * 4 + wave;
        float4 w4 = *(const float4*)&W[(size_t)k * N + lane * 4];
        float4 e4 = *(const float4*)&emb_w[lane * 4];
        float s = w4.x * e4.x + w4.y * e4.y + w4.z * e4.z + w4.w * e4.w;
        #pragma unroll
        for (int d = 32; d; d >>= 1) s += __shfl_down(s, d);
        if (lane == 0) q[k] = s;
    } else if (b < nq + (K / 32) * (N / 32)) {
        __shared__ float ts[32][33];
        int idx = b - nq;
        int k0 = (idx % (K / 32)) * 32;
        int n0 = (idx / (K / 32)) * 32;
        int x = threadIdx.x & 31, y = threadIdx.x >> 5;
        #pragma unroll
        for (int i = 0; i < 4; ++i) {
            int kk = y + i * 8;
            ts[kk][x] = W[(size_t)(k0 + kk) * N + n0 + x];
        }
        __syncthreads();
        #pragma unroll
        for (int i = 0; i < 4; ++i) {
            int nn = y + i * 8;
            Wt[(size_t)(n0 + nn) * K + k0 + x] = f2bf(ts[x][nn]);
        }
    } else {
        if (threadIdx.x == 0) *done = 0;
    }
}

__global__ __launch_bounds__(256) void k_hp(const float* __restrict__ H,
                                            const float* __restrict__ q,
                                            const float* __restrict__ emb_b,
                                            const float* __restrict__ rv,
                                            ushort* __restrict__ Hb,
                                            float* __restrict__ p, int M, int K) {
    int wid = threadIdx.x >> 6, lane = threadIdx.x & 63;
    int i = blockIdx.x * 4 + wid;
    if (i >= M) return;
    const float* h = H + (size_t)i * K;
    float s = 0.f;
    for (int o = lane * 8; o < K; o += 512) {
        float4 a = *(const float4*)&h[o];
        float4 b = *(const float4*)&h[o + 4];
        float4 qa = *(const float4*)&q[o];
        float4 qb = *(const float4*)&q[o + 4];
        s += a.x * qa.x + a.y * qa.y + a.z * qa.z + a.w * qa.w
           + b.x * qb.x + b.y * qb.y + b.z * qb.z + b.w * qb.w;
        ushort u[8] = {f2bf(a.x), f2bf(a.y), f2bf(a.z), f2bf(a.w),
                       f2bf(b.x), f2bf(b.y), f2bf(b.z), f2bf(b.w)};
        *(int4*)&Hb[(size_t)i * K + o] = *(int4*)u;
    }
    #pragma unroll
    for (int d = 32; d; d >>= 1) s += __shfl_down(s, d);
    if (lane == 0) p[i] = (s + emb_b[0]) * rv[0];
}

__global__ __launch_bounds__(256) void k_hist_mm(const int* __restrict__ st,
                                                 const float* __restrict__ p,
                                                 uint* __restrict__ parthist,
                                                 const ushort* __restrict__ Hb,
                                                 const ushort* __restrict__ Wt,
                                                 ushort* __restrict__ HWb,
                                                 int E, int M, int N, int K) {
    extern __shared__ char smem[];
    int b = blockIdx.x;
    if (b >= NB) { mm_tile(b - NB, smem, Hb, Wt, HWb, M, N, K); return; }
    uint* h = (uint*)smem;
    for (int i = threadIdx.x; i < M; i += 256) h[i] = 0;
    __syncthreads();
    int epb = (E + NB - 1) / NB;
    int beg = b * epb, end = min(beg + epb, E);
    for (int e = beg + threadIdx.x; e < end; e += 256) {
        int u = st[e], v = st[E + e];
        uint inc = (p[u] > p[v]) ? 1u : (1u << 16);
        atomicAdd(&h[u], inc);
        atomicAdd(&h[v], inc);
    }
    __syncthreads();
    for (int i = threadIdx.x; i < M; i += 256)
        parthist[(size_t)b * M + i] = h[i];
}

__global__ __launch_bounds__(256) void k_merge_scan_mm(uint* __restrict__ parthist,
                                                       int* __restrict__ crosscnt,
                                                       float* __restrict__ selfmul,
                                                       int* __restrict__ offsets,
                                                       uint* __restrict__ done,
                                                       const ushort* __restrict__ Hb,
                                                       const ushort* __restrict__ Wt,
                                                       ushort* __restrict__ HWb,
                                                       int M, int N, int K,
                                                       int nmerge, int mmoff) {
    extern __shared__ char smem[];
    int b = blockIdx.x;
    if (b >= nmerge) { mm_tile(b - nmerge + mmoff, smem, Hb, Wt, HWb, M, N, K); return; }
    int r = b * 256 + threadIdx.x;
    if (r < M) {
        uint crun = 0, srun = 0;
        for (int c = 0; c < NB / 32; ++c) {
            uint vals[32];
            #pragma unroll
            for (int i = 0; i < 32; ++i)
                vals[i] = parthist[(size_t)(c * 32 + i) * M + r];
            #pragma unroll
            for (int i = 0; i < 32; ++i) {
                parthist[(size_t)(c * 32 + i) * M + r] = crun;
                crun += vals[i] & 0xFFFFu;
                srun += vals[i] >> 16;
            }
        }
        crosscnt[r] = (int)crun;
        selfmul[r] = 1.0f + (float)srun;
    }
    __threadfence();
    __shared__ uint ticket;
    if (threadIdx.x == 0) ticket = atomicAdd(done, 1);
    __syncthreads();
    if (ticket == (uint)(nmerge - 1)) {
        __threadfence();
        __shared__ int s[256];
        int t = threadIdx.x;
        int chunk = (M + 255) / 256;
        int cb = t * chunk;
        int ce = min(cb + chunk, M);
        int sum = 0;
        for (int i = cb; i < ce; ++i) sum += crosscnt[i];
        s[t] = sum;
        __syncthreads();
        for (int d = 1; d < 256; d <<= 1) {
            int val = (t >= d) ? s[t - d] : 0;
            __syncthreads();
            s[t] += val;
            __syncthreads();
        }
        int run = (t == 0) ? 0 : s[t - 1];
        for (int i = cb; i < ce; ++i) {
            offsets[i] = run;
            run += crosscnt[i];
        }
        if (t == 255) offsets[M] = run;
    }
}

__global__ __launch_bounds__(256) void k_fill_mm(const int* __restrict__ st,
                                                 const float* __restrict__ p,
                                                 const int* __restrict__ offsets,
                                                 const uint* __restrict__ blockbase,
                                                 int* __restrict__ colidx,
                                                 const ushort* __restrict__ Hb,
                                                 const ushort* __restrict__ Wt,
                                                 ushort* __restrict__ HWb,
                                                 int E, int M, int N, int K, int mmoff) {
    extern __shared__ char smem[];
    int b = blockIdx.x;
    if (b >= NB) { mm_tile(b - NB + mmoff, smem, Hb, Wt, HWb, M, N, K); return; }
    int* cur = (int*)smem;
    for (int i = threadIdx.x; i < M; i += 256)
        cur[i] = offsets[i] + (int)blockbase[(size_t)b * M + i];
    __syncthreads();
    int epb = (E + NB - 1) / NB;
    int beg = b * epb, end = min(beg + epb, E);
    for (int e = beg + threadIdx.x; e < end; e += 256) {
        int u = st[e], v = st[E + e];
        if (p[u] > p[v]) {
            int su = atomicAdd(&cur[u], 1);
            colidx[su] = v;
            int sv = atomicAdd(&cur[v], 1);
            colidx[sv] = u;
        }
    }
}

// ---------------------------------------------------------------------------
// out[r,:] = bf2f(HWb[r,:]) * selfmul[r] + bias + sum_j bf2f(HWb[colidx[j],:])
__global__ __launch_bounds__(256) void k_gather(const ushort* __restrict__ HWb,
                                                const float* __restrict__ bias,
                                                const float* __restrict__ selfmul,
                                                const int* __restrict__ offs,
                                                const int* __restrict__ colidx,
                                                float* __restrict__ out, int N, int M) {
    int wid = threadIdx.x >> 6, lane = threadIdx.x & 63;
    int r = blockIdx.x * 4 + wid;
    if (r >= M) return;
    int beg = offs[r], end = offs[r + 1];
    float a0 = 0.f, a1 = 0.f, a2 = 0.f, a3 = 0.f;
    float b0 = 0.f, b1 = 0.f, b2 = 0.f, b3 = 0.f;
    int j = beg;
    for (; j + 8 <= end; j += 8) {
        int c8 = colidx[j + (lane & 7)];
        #pragma unroll
        for (int i = 0; i < 8; i += 2) {
            int ca = __shfl(c8, i, 8);
            int cb = __shfl(c8, i + 1, 8);
            ushort4 ma = *(const ushort4*)&HWb[(size_t)ca * N + lane * 4];
            ushort4 mb = *(const ushort4*)&HWb[(size_t)cb * N + lane * 4];
            a0 += bf2f(ma.x); a1 += bf2f(ma.y); a2 += bf2f(ma.z); a3 += bf2f(ma.w);
            b0 += bf2f(mb.x); b1 += bf2f(mb.y); b2 += bf2f(mb.z); b3 += bf2f(mb.w);
        }
    }
    for (; j < end; ++j) {
        int c = colidx[j];
        ushort4 m = *(const ushort4*)&HWb[(size_t)c * N + lane * 4];
        a0 += bf2f(m.x); a1 += bf2f(m.y); a2 += bf2f(m.z); a3 += bf2f(m.w);
    }
    ushort4 mi = *(const ushort4*)&HWb[(size_t)r * N + lane * 4];
    float4 bi = *(const float4*)&bias[lane * 4];
    float sm = selfmul[r];
    float4 o;
    o.x = bf2f(mi.x) * sm + bi.x + a0 + b0;
    o.y = bf2f(mi.y) * sm + bi.y + a1 + b1;
    o.z = bf2f(mi.z) * sm + bi.z + a2 + b2;
    o.w = bf2f(mi.w) * sm + bi.w + a3 + b3;
    *(float4*)&out[(size_t)r * N + lane * 4] = o;
}

// ---------------------------------------------------------------------------
extern "C" void kernel_launch(void* const* d_in, const int* in_sizes, int n_in,
                              void* d_out, int out_size, void* d_ws, size_t ws_size,
                              hipStream_t stream) {
    const int*   st    = (const int*)d_in[0];
    const float* H     = (const float*)d_in[1];
    const float* W     = (const float*)d_in[2];
    const float* bias  = (const float*)d_in[3];
    const float* emb_w = (const float*)d_in[4];
    const float* emb_b = (const float*)d_in[5];
    const float* rv    = (const float*)d_in[6];
    float* out = (float*)d_out;

    const int E = in_sizes[0] / 2;       // 320000
    const int N = in_sizes[3];           // 256
    const int K = in_sizes[2] / N;       // 512
    const int M = in_sizes[1] / K;       // 10000  (<= MCAP)

    char* ws = (char*)d_ws;
    size_t off = 0;
    auto alloc = [&](size_t bytes) -> char* {
        char* ptr = ws + off;
        off = (off + bytes + 255) & ~(size_t)255;
        return ptr;
    };
    float*  q        = (float*)alloc((size_t)K * 4);
    float*  p        = (float*)alloc((size_t)M * 4);
    ushort* HWb      = (ushort*)alloc((size_t)M * N * 2);
    ushort* Hb       = (ushort*)alloc((size_t)M * K * 2);
    ushort* Wt       = (ushort*)alloc((size_t)K * N * 2);
    uint*   parthist = (uint*)alloc((size_t)NB * M * 4);
    int*    crosscnt = (int*)alloc((size_t)M * 4);
    float*  selfmul  = (float*)alloc((size_t)M * 4);
    int*    offsets  = (int*)alloc((size_t)(M + 1) * 4);
    int*    colidx   = (int*)alloc((size_t)2 * E * 4);
    uint*   done     = (uint*)alloc(256);
    uint*   tileCtr  = (uint*)alloc(256);
    (void)ws_size; (void)n_in; (void)out_size;

    const int tiles = ((M + 127) / 128) * (N / 128);   // 158

    // ---- try the cooperative fused path, sized by queried occupancy ----
    bool coop_ok = false;
    {
        int dev = 0;
        hipGetDevice(&dev);
        int numCU = 0;
        hipDeviceGetAttribute(&numCU, hipDeviceAttributeMultiprocessorCount, dev);
        int maxB = 0;
        hipError_t oe = hipOccupancyMaxActiveBlocksPerMultiprocessor(
            &maxB, k_mega, 256, (size_t)DYN_LDS);
        int G = 0;
        if (oe == hipSuccess && numCU > 0) G = maxB * numCU;
        if (G > GMAX) G = GMAX;
        if (G >= NB) {
            int Ei = E, Mi = M, Ni = N, Ki = K, Ti = tiles;
            void* kargs[] = {(void*)&st, (void*)&H, (void*)&W, (void*)&emb_w,
                             (void*)&emb_b, (void*)&rv, (void*)&q, (void*)&p,
                             (void*)&Hb, (void*)&Wt, (void*)&HWb, (void*)&parthist,
                             (void*)&crosscnt, (void*)&selfmul, (void*)&offsets,
                             (void*)&colidx, (void*)&tileCtr,
                             (void*)&Ei, (void*)&Mi, (void*)&Ni, (void*)&Ki, (void*)&Ti};
            hipError_t le = hipLaunchCooperativeKernel((void*)k_mega, dim3(G), dim3(256),
                                                       kargs, DYN_LDS, stream);
            coop_ok = (le == hipSuccess);
        }
    }

    // ---- fallback: verified multi-kernel pipeline (R6) ----
    if (!coop_ok) {
        const int nmerge = (M + 255) / 256;
        const int mmA = (tiles * 2) / 5;
        const int mmB = tiles / 4;
        const int mmC = tiles - mmA - mmB;
        k_prep<<<K / 4 + (K / 32) * (N / 32) + 1, 256, 0, stream>>>(W, emb_w, q, Wt, done, K, N);
        k_hp<<<(M + 3) / 4, 256, 0, stream>>>(H, q, emb_b, rv, Hb, p, M, K);
        k_hist_mm<<<NB + mmA, 256, DYN_LDS, stream>>>(st, p, parthist, Hb, Wt, HWb, E, M, N, K);
        k_merge_scan_mm<<<nmerge + mmB, 256, DYN_LDS, stream>>>(parthist, crosscnt, selfmul,
                                                                offsets, done, Hb, Wt, HWb,
                                                                M, N, K, nmerge, mmA);
        k_fill_mm<<<NB + mmC, 256, DYN_LDS, stream>>>(st, p, offsets, parthist, colidx,
                                                      Hb, Wt, HWb, E, M, N, K, mmA + mmB);
    }

    k_gather<<<(M + 3) / 4, 256, 0, stream>>>(HWb, bias, selfmul, offsets, colidx, out, N, M);
}

// Round 9
// 97.413 us; speedup vs baseline: 3.8351x; 3.8351x over previous
//
#include <hip/hip_runtime.h>
#include <hip/hip_bf16.h>

// n=M=10000 nodes, a=K=512, b=N=256, E=320000 edges.  M must be <= MCAP.

#define NB   64    // edge-partition blocks for hist/fill
#define MCAP 10240
#define DYN_LDS 40960

typedef __attribute__((ext_vector_type(8))) short bf16x8;
typedef __attribute__((ext_vector_type(4))) float f32x4;

__device__ inline ushort f2bf(float f) {
    uint b = __float_as_uint(f);
    return (ushort)((b + 0x7FFFu + ((b >> 16) & 1u)) >> 16);  // RNE
}
__device__ inline float bf2f(ushort u) { return __uint_as_float((uint)u << 16); }

// ---------------------------------------------------------------------------
// MFMA GEMM tile (128x128, 4 waves x 4x4 frags of 16x16x32 bf16).
__device__ void mm_tile(int tile, char* smem,
                        const ushort* __restrict__ Hb,
                        const ushort* __restrict__ Wt,
                        ushort* __restrict__ HWb, int M, int N, int K) {
    ushort (*As)[40] = (ushort (*)[40])smem;
    ushort (*Bs)[40] = (ushort (*)[40])(smem + 128 * 40 * 2);
    int mblk = (M + 127) >> 7;
    int m0 = (tile % mblk) * 128, n0 = (tile / mblk) * 128;
    int tid = threadIdx.x;
    int wid = tid >> 6, lane = tid & 63;
    int wm = (wid >> 1) * 64, wn = (wid & 1) * 64;
    int frow = lane & 15, fg = (lane >> 4) * 8;
    f32x4 acc[4][4] = {};
    for (int k0 = 0; k0 < K; k0 += 32) {
        #pragma unroll
        for (int h = 0; h < 2; ++h) {
            int chunk = tid + 256 * h;
            int row = chunk >> 2, kc = (chunk & 3) * 8;
            int gr = m0 + row;
            int4 va = make_int4(0, 0, 0, 0);
            if (gr < M) va = *(const int4*)&Hb[(size_t)gr * K + k0 + kc];
            *(int4*)&As[row][kc] = va;
            int4 vb = *(const int4*)&Wt[(size_t)(n0 + row) * K + k0 + kc];
            *(int4*)&Bs[row][kc] = vb;
        }
        __syncthreads();
        bf16x8 av[4], bv[4];
        #pragma unroll
        for (int i = 0; i < 4; ++i)
            av[i] = *(const bf16x8*)&As[wm + i * 16 + frow][fg];
        #pragma unroll
        for (int j = 0; j < 4; ++j)
            bv[j] = *(const bf16x8*)&Bs[wn + j * 16 + frow][fg];
        #pragma unroll
        for (int i = 0; i < 4; ++i)
            #pragma unroll
            for (int j = 0; j < 4; ++j)
                acc[i][j] = __builtin_amdgcn_mfma_f32_16x16x32_bf16(av[i], bv[j], acc[i][j], 0, 0, 0);
        __syncthreads();
    }
    // C/D map: col=lane&15, row=(lane>>4)*4+rr  [verified m89/m91]
    int orow = (lane >> 4) * 4, ocol = lane & 15;
    #pragma unroll
    for (int i = 0; i < 4; ++i) {
        #pragma unroll
        for (int rr = 0; rr < 4; ++rr) {
            int grow = m0 + wm + i * 16 + orow + rr;
            if (grow < M) {
                #pragma unroll
                for (int j = 0; j < 4; ++j) {
                    int gcol = n0 + wn + j * 16 + ocol;
                    HWb[(size_t)grow * N + gcol] = f2bf(acc[i][j][rr]);
                }
            }
        }
    }
}

// ---------------------------------------------------------------------------
// Prelude: q = W @ emb_w (f32-exact routing path); Wt = bf16(W^T); done = 0
__global__ __launch_bounds__(256) void k_prep(const float* __restrict__ W,
                                              const float* __restrict__ emb_w,
                                              float* __restrict__ q,
                                              ushort* __restrict__ Wt,
                                              uint* __restrict__ done,
                                              int K, int N) {
    int b = blockIdx.x;
    int nq = K / 4;
    if (b < nq) {
        int wave = threadIdx.x >> 6;
        int lane = threadIdx.x & 63;
        int k = b * 4 + wave;
        float4 w4 = *(const float4*)&W[(size_t)k * N + lane * 4];
        float4 e4 = *(const float4*)&emb_w[lane * 4];
        float s = w4.x * e4.x + w4.y * e4.y + w4.z * e4.z + w4.w * e4.w;
        #pragma unroll
        for (int d = 32; d; d >>= 1) s += __shfl_down(s, d);
        if (lane == 0) q[k] = s;
    } else if (b < nq + (K / 32) * (N / 32)) {
        __shared__ float ts[32][33];
        int idx = b - nq;
        int k0 = (idx % (K / 32)) * 32;
        int n0 = (idx / (K / 32)) * 32;
        int x = threadIdx.x & 31, y = threadIdx.x >> 5;
        #pragma unroll
        for (int i = 0; i < 4; ++i) {
            int kk = y + i * 8;
            ts[kk][x] = W[(size_t)(k0 + kk) * N + n0 + x];
        }
        __syncthreads();
        #pragma unroll
        for (int i = 0; i < 4; ++i) {
            int nn = y + i * 8;
            Wt[(size_t)(n0 + nn) * K + k0 + x] = f2bf(ts[x][nn]);
        }
    } else {
        if (threadIdx.x == 0) *done = 0;
    }
}

// Fused: Hb = bf16(H)  AND  p[i] = (dot(H[i,:], q) + emb_b) * rv  (f32-exact)
__global__ __launch_bounds__(256) void k_hp(const float* __restrict__ H,
                                            const float* __restrict__ q,
                                            const float* __restrict__ emb_b,
                                            const float* __restrict__ rv,
                                            ushort* __restrict__ Hb,
                                            float* __restrict__ p, int M, int K) {
    int wid = threadIdx.x >> 6, lane = threadIdx.x & 63;
    int i = blockIdx.x * 4 + wid;
    if (i >= M) return;
    const float* h = H + (size_t)i * K;
    float s = 0.f;
    for (int o = lane * 8; o < K; o += 512) {
        float4 a = *(const float4*)&h[o];
        float4 b = *(const float4*)&h[o + 4];
        float4 qa = *(const float4*)&q[o];
        float4 qb = *(const float4*)&q[o + 4];
        s += a.x * qa.x + a.y * qa.y + a.z * qa.z + a.w * qa.w
           + b.x * qb.x + b.y * qb.y + b.z * qb.z + b.w * qb.w;
        ushort u[8] = {f2bf(a.x), f2bf(a.y), f2bf(a.z), f2bf(a.w),
                       f2bf(b.x), f2bf(b.y), f2bf(b.z), f2bf(b.w)};
        *(int4*)&Hb[(size_t)i * K + o] = *(int4*)u;
    }
    #pragma unroll
    for (int d = 32; d; d >>= 1) s += __shfl_down(s, d);
    if (lane == 0) p[i] = (s + emb_b[0]) * rv[0];
}

// ---------------------------------------------------------------------------
// Launch A: blocks [0,NB) = per-block LDS histogram (cross lo16 / self hi16);
//           blocks [NB, NB+tiles) = ALL mm tiles (one tile per block).
__global__ __launch_bounds__(256) void k_hist_mm(const int* __restrict__ st,
                                                 const float* __restrict__ p,
                                                 uint* __restrict__ parthist,
                                                 const ushort* __restrict__ Hb,
                                                 const ushort* __restrict__ Wt,
                                                 ushort* __restrict__ HWb,
                                                 int E, int M, int N, int K) {
    extern __shared__ char smem[];
    int b = blockIdx.x;
    if (b >= NB) { mm_tile(b - NB, smem, Hb, Wt, HWb, M, N, K); return; }
    uint* h = (uint*)smem;
    for (int i = threadIdx.x; i < M; i += 256) h[i] = 0;
    __syncthreads();
    int epb = (E + NB - 1) / NB;
    int beg = b * epb, end = min(beg + epb, E);
    for (int e = beg + threadIdx.x; e < end; e += 256) {
        int u = st[e], v = st[E + e];
        uint inc = (p[u] > p[v]) ? 1u : (1u << 16);
        atomicAdd(&h[u], inc);
        atomicAdd(&h[v], inc);
    }
    __syncthreads();
    for (int i = threadIdx.x; i < M; i += 256)
        parthist[(size_t)b * M + i] = h[i];
}

// Launch B: per-row merge over NB partials (batched 32-wide loads, in-place
// exclusive cross prefix); LAST block (device ticket) does the global scan.
__global__ __launch_bounds__(256) void k_merge_scan(uint* __restrict__ parthist,
                                                    int* __restrict__ crosscnt,
                                                    float* __restrict__ selfmul,
                                                    int* __restrict__ offsets,
                                                    uint* __restrict__ done,
                                                    int M, int nmerge) {
    int b = blockIdx.x;
    int r = b * 256 + threadIdx.x;
    if (r < M) {
        uint crun = 0, srun = 0;
        for (int c = 0; c < NB / 32; ++c) {
            uint vals[32];
            #pragma unroll
            for (int i = 0; i < 32; ++i)
                vals[i] = parthist[(size_t)(c * 32 + i) * M + r];
            #pragma unroll
            for (int i = 0; i < 32; ++i) {
                parthist[(size_t)(c * 32 + i) * M + r] = crun;
                crun += vals[i] & 0xFFFFu;
                srun += vals[i] >> 16;
            }
        }
        crosscnt[r] = (int)crun;
        selfmul[r] = 1.0f + (float)srun;
    }
    __threadfence();
    __shared__ uint ticket;
    if (threadIdx.x == 0) ticket = atomicAdd(done, 1);
    __syncthreads();
    if (ticket == (uint)(nmerge - 1)) {
        __threadfence();
        __shared__ int s[256];
        int t = threadIdx.x;
        int chunk = (M + 255) / 256;
        int cb = t * chunk;
        int ce = min(cb + chunk, M);
        int sum = 0;
        for (int i = cb; i < ce; ++i) sum += crosscnt[i];
        s[t] = sum;
        __syncthreads();
        for (int d = 1; d < 256; d <<= 1) {
            int val = (t >= d) ? s[t - d] : 0;
            __syncthreads();
            s[t] += val;
            __syncthreads();
        }
        int run = (t == 0) ? 0 : s[t - 1];
        for (int i = cb; i < ce; ++i) {
            offsets[i] = run;
            run += crosscnt[i];
        }
        if (t == 255) offsets[M] = run;
    }
}

// Launch C: slot assignment (LDS cursors; cross edges only).
__global__ __launch_bounds__(256) void k_fill(const int* __restrict__ st,
                                              const float* __restrict__ p,
                                              const int* __restrict__ offsets,
                                              const uint* __restrict__ blockbase,
                                              int* __restrict__ colidx,
                                              int E, int M) {
    extern __shared__ char smem[];
    int b = blockIdx.x;
    int* cur = (int*)smem;
    for (int i = threadIdx.x; i < M; i += 256)
        cur[i] = offsets[i] + (int)blockbase[(size_t)b * M + i];
    __syncthreads();
    int epb = (E + NB - 1) / NB;
    int beg = b * epb, end = min(beg + epb, E);
    for (int e = beg + threadIdx.x; e < end; e += 256) {
        int u = st[e], v = st[E + e];
        if (p[u] > p[v]) {
            int su = atomicAdd(&cur[u], 1);
            colidx[su] = v;
            int sv = atomicAdd(&cur[v], 1);
            colidx[sv] = u;
        }
    }
}

// ---------------------------------------------------------------------------
// out[r,:] = bf2f(HWb[r,:]) * selfmul[r] + bias + sum_j bf2f(HWb[colidx[j],:])
// One WAVE per row; unroll-16 message loop (4 accumulator groups -> 16
// outstanding 8B row-reads/lane), coalesced colidx load + shfl broadcast.
__global__ __launch_bounds__(256) void k_gather(const ushort* __restrict__ HWb,
                                                const float* __restrict__ bias,
                                                const float* __restrict__ selfmul,
                                                const int* __restrict__ offs,
                                                const int* __restrict__ colidx,
                                                float* __restrict__ out, int N, int M) {
    int wid = threadIdx.x >> 6, lane = threadIdx.x & 63;
    int r = blockIdx.x * 4 + wid;
    if (r >= M) return;
    int beg = offs[r], end = offs[r + 1];
    float a0 = 0.f, a1 = 0.f, a2 = 0.f, a3 = 0.f;
    float b0 = 0.f, b1 = 0.f, b2 = 0.f, b3 = 0.f;
    float c0 = 0.f, c1 = 0.f, c2 = 0.f, c3 = 0.f;
    float d0 = 0.f, d1 = 0.f, d2 = 0.f, d3 = 0.f;
    int j = beg;
    for (; j + 16 <= end; j += 16) {
        int c16 = colidx[j + (lane & 15)];
        #pragma unroll
        for (int i = 0; i < 16; i += 4) {
            int ca = __shfl(c16, i,     16);
            int cb = __shfl(c16, i + 1, 16);
            int cc = __shfl(c16, i + 2, 16);
            int cd = __shfl(c16, i + 3, 16);
            ushort4 ma = *(const ushort4*)&HWb[(size_t)ca * N + lane * 4];
            ushort4 mb = *(const ushort4*)&HWb[(size_t)cb * N + lane * 4];
            ushort4 mc = *(const ushort4*)&HWb[(size_t)cc * N + lane * 4];
            ushort4 md = *(const ushort4*)&HWb[(size_t)cd * N + lane * 4];
            a0 += bf2f(ma.x); a1 += bf2f(ma.y); a2 += bf2f(ma.z); a3 += bf2f(ma.w);
            b0 += bf2f(mb.x); b1 += bf2f(mb.y); b2 += bf2f(mb.z); b3 += bf2f(mb.w);
            c0 += bf2f(mc.x); c1 += bf2f(mc.y); c2 += bf2f(mc.z); c3 += bf2f(mc.w);
            d0 += bf2f(md.x); d1 += bf2f(md.y); d2 += bf2f(md.z); d3 += bf2f(md.w);
        }
    }
    for (; j + 8 <= end; j += 8) {
        int c8 = colidx[j + (lane & 7)];
        #pragma unroll
        for (int i = 0; i < 8; i += 2) {
            int ca = __shfl(c8, i, 8);
            int cb = __shfl(c8, i + 1, 8);
            ushort4 ma = *(const ushort4*)&HWb[(size_t)ca * N + lane * 4];
            ushort4 mb = *(const ushort4*)&HWb[(size_t)cb * N + lane * 4];
            a0 += bf2f(ma.x); a1 += bf2f(ma.y); a2 += bf2f(ma.z); a3 += bf2f(ma.w);
            b0 += bf2f(mb.x); b1 += bf2f(mb.y); b2 += bf2f(mb.z); b3 += bf2f(mb.w);
        }
    }
    for (; j < end; ++j) {
        int c = colidx[j];
        ushort4 m = *(const ushort4*)&HWb[(size_t)c * N + lane * 4];
        a0 += bf2f(m.x); a1 += bf2f(m.y); a2 += bf2f(m.z); a3 += bf2f(m.w);
    }
    ushort4 mi = *(const ushort4*)&HWb[(size_t)r * N + lane * 4];
    float4 bi = *(const float4*)&bias[lane * 4];
    float sm = selfmul[r];
    float4 o;
    o.x = bf2f(mi.x) * sm + bi.x + (a0 + b0) + (c0 + d0);
    o.y = bf2f(mi.y) * sm + bi.y + (a1 + b1) + (c1 + d1);
    o.z = bf2f(mi.z) * sm + bi.z + (a2 + b2) + (c2 + d2);
    o.w = bf2f(mi.w) * sm + bi.w + (a3 + b3) + (c3 + d3);
    *(float4*)&out[(size_t)r * N + lane * 4] = o;
}

// ---------------------------------------------------------------------------
extern "C" void kernel_launch(void* const* d_in, const int* in_sizes, int n_in,
                              void* d_out, int out_size, void* d_ws, size_t ws_size,
                              hipStream_t stream) {
    const int*   st    = (const int*)d_in[0];
    const float* H     = (const float*)d_in[1];
    const float* W     = (const float*)d_in[2];
    const float* bias  = (const float*)d_in[3];
    const float* emb_w = (const float*)d_in[4];
    const float* emb_b = (const float*)d_in[5];
    const float* rv    = (const float*)d_in[6];
    float* out = (float*)d_out;

    const int E = in_sizes[0] / 2;       // 320000
    const int N = in_sizes[3];           // 256
    const int K = in_sizes[2] / N;       // 512
    const int M = in_sizes[1] / K;       // 10000  (<= MCAP)

    char* ws = (char*)d_ws;
    size_t off = 0;
    auto alloc = [&](size_t bytes) -> char* {
        char* ptr = ws + off;
        off = (off + bytes + 255) & ~(size_t)255;
        return ptr;
    };
    float*  q        = (float*)alloc((size_t)K * 4);
    float*  p        = (float*)alloc((size_t)M * 4);
    ushort* HWb      = (ushort*)alloc((size_t)M * N * 2);
    ushort* Hb       = (ushort*)alloc((size_t)M * K * 2);
    ushort* Wt       = (ushort*)alloc((size_t)K * N * 2);
    uint*   parthist = (uint*)alloc((size_t)NB * M * 4);
    int*    crosscnt = (int*)alloc((size_t)M * 4);
    float*  selfmul  = (float*)alloc((size_t)M * 4);
    int*    offsets  = (int*)alloc((size_t)(M + 1) * 4);
    int*    colidx   = (int*)alloc((size_t)2 * E * 4);
    uint*   done     = (uint*)alloc(256);
    (void)ws_size; (void)n_in; (void)out_size;

    const int tiles  = ((M + 127) / 128) * (N / 128);   // 158
    const int nmerge = (M + 255) / 256;                 // 40

    k_prep<<<K / 4 + (K / 32) * (N / 32) + 1, 256, 0, stream>>>(W, emb_w, q, Wt, done, K, N);
    k_hp<<<(M + 3) / 4, 256, 0, stream>>>(H, q, emb_b, rv, Hb, p, M, K);
    k_hist_mm<<<NB + tiles, 256, DYN_LDS, stream>>>(st, p, parthist, Hb, Wt, HWb, E, M, N, K);
    k_merge_scan<<<nmerge, 256, 0, stream>>>(parthist, crosscnt, selfmul, offsets, done, M, nmerge);
    k_fill<<<NB, 256, DYN_LDS, stream>>>(st, p, offsets, parthist, colidx, E, M);
    k_gather<<<(M + 3) / 4, 256, 0, stream>>>(HWb, bias, selfmul, offsets, colidx, out, N, M);
}